// Round 1
// baseline (597.221 us; speedup 1.0000x reference)
//
#include <hip/hip_runtime.h>

#define N 8192
#define F 128
#define TM 32
#define TK 64
#define ALPHA 0.2f

__device__ __forceinline__ float lrelu(float z) { return z > 0.f ? z : ALPHA * z; }

// ---------------- K1: h = x @ W  (fp32, 32-row tiles, k-chunked W staging) ----------------
__global__ __launch_bounds__(256) void gemm_h(const float* __restrict__ x,
                                              const float* __restrict__ W,
                                              float* __restrict__ h) {
    __shared__ float xs[TM * 128];   // 16 KB
    __shared__ float Wsh[32 * 128];  // 16 KB
    const int t = threadIdx.x;
    const int i0 = blockIdx.x * TM;
    const int c4 = (t & 31) * 4;
    const int r8 = t >> 5;

#pragma unroll
    for (int p = 0; p < 4; ++p) {
        int rr = p * 8 + r8;
        *(float4*)&xs[rr * 128 + c4] = *(const float4*)&x[(i0 + rr) * 128 + c4];
    }

    const int tx = t & 31, ty = t >> 5;
    const int r0 = ty * 4, c0 = tx * 4;
    float acc[4][4] = {};

    for (int kc = 0; kc < 4; ++kc) {
        __syncthreads();  // xs ready (kc=0) / previous Wsh reads done
#pragma unroll
        for (int p = 0; p < 4; ++p) {
            int k = p * 8 + r8;
            *(float4*)&Wsh[k * 128 + c4] = *(const float4*)&W[(kc * 32 + k) * 128 + c4];
        }
        __syncthreads();
#pragma unroll 4
        for (int k = 0; k < 32; k += 4) {
            float xr[4][4];
#pragma unroll
            for (int rr = 0; rr < 4; ++rr)
                *(float4*)xr[rr] = *(const float4*)&xs[(r0 + rr) * 128 + kc * 32 + k];
#pragma unroll
            for (int kk = 0; kk < 4; ++kk) {
                float4 wv = *(const float4*)&Wsh[(k + kk) * 128 + c0];
#pragma unroll
                for (int rr = 0; rr < 4; ++rr) {
                    acc[rr][0] += xr[rr][kk] * wv.x;
                    acc[rr][1] += xr[rr][kk] * wv.y;
                    acc[rr][2] += xr[rr][kk] * wv.z;
                    acc[rr][3] += xr[rr][kk] * wv.w;
                }
            }
        }
    }
#pragma unroll
    for (int rr = 0; rr < 4; ++rr) {
        float4 o = {acc[rr][0], acc[rr][1], acc[rr][2], acc[rr][3]};
        *(float4*)&h[(i0 + r0 + rr) * 128 + c0] = o;
    }
}

// ---------------- K2: s_src[i] = h[i,:]@a[0:128], s_dst[i] = h[i,:]@a[128:256] ----------------
__global__ __launch_bounds__(256) void scores(const float* __restrict__ h,
                                              const float* __restrict__ a,
                                              float* __restrict__ ssrc,
                                              float* __restrict__ sdst) {
    const int t = threadIdx.x;
    const int lane = t & 63;
    const int row = blockIdx.x * 4 + (t >> 6);
    float h0 = h[row * F + lane];
    float h1 = h[row * F + 64 + lane];
    float vs = h0 * a[lane] + h1 * a[64 + lane];
    float vd = h0 * a[F + lane] + h1 * a[F + 64 + lane];
#pragma unroll
    for (int off = 32; off >= 1; off >>= 1) {
        vs += __shfl_down(vs, off);
        vd += __shfl_down(vd, off);
    }
    if (lane == 0) {
        ssrc[row] = vs;
        sdst[row] = vd;
    }
}

// ---------------- K3: partial out[i,:] = sum_j w_ij h[j,:],  pS = sum_j w_ij ----------------
// grid (N/TM, 2): blockIdx.y selects j-half. Split 0 accumulates into d_out, split 1 into pacc1.
__global__ __launch_bounds__(256) void attn_kernel(const int* __restrict__ adj,
                                                   const float* __restrict__ h,
                                                   const float* __restrict__ ssrc,
                                                   const float* __restrict__ sdst,
                                                   float* __restrict__ out,
                                                   float* __restrict__ pacc1,
                                                   float* __restrict__ pS) {
    __shared__ float hs[TK * F];   // 32 KB
    __shared__ float wsh[TM * TK]; // 8 KB
    __shared__ float si[TM];

    const int t = threadIdx.x;
    const int i0 = blockIdx.x * TM;
    const int split = blockIdx.y;
    const int jbase = split * (N / 2);

    if (t < TM) si[t] = ssrc[i0 + t];

    const int tx = t & 31, ty = t >> 5;
    const int r0 = ty * 4, c0 = tx * 4;
    const int wk4 = (t & 15) * 4;  // k-slice within chunk for w staging
    const int wi = t >> 4;         // row 0..15 (and +16 on second pass)

    float acc[4][4] = {};
    float rS0 = 0.f, rS1 = 0.f;

    __syncthreads();  // si visible

    for (int jc = 0; jc < (N / 2) / TK; ++jc) {
        const int j0 = jbase + jc * TK;

        // stage h tile: 64 rows x 128 cols
#pragma unroll
        for (int p = 0; p < 8; ++p) {
            int jr = p * 8 + ty;
            *(float4*)&hs[jr * F + c0] = *(const float4*)&h[(size_t)(j0 + jr) * F + c0];
        }

        // stage w tile: compute from adj + scores; also accumulate row sums
        float4 sdv = *(const float4*)&sdst[j0 + wk4];
#pragma unroll
        for (int p = 0; p < 2; ++p) {
            int ii = wi + p * 16;
            int4 av = *(const int4*)&adj[(size_t)(i0 + ii) * N + j0 + wk4];
            float sv = si[ii];
            float w0 = av.x > 0 ? __expf(lrelu(sv + sdv.x)) : 0.f;
            float w1 = av.y > 0 ? __expf(lrelu(sv + sdv.y)) : 0.f;
            float w2 = av.z > 0 ? __expf(lrelu(sv + sdv.z)) : 0.f;
            float w3 = av.w > 0 ? __expf(lrelu(sv + sdv.w)) : 0.f;
            float4 wv4 = {w0, w1, w2, w3};
            *(float4*)&wsh[ii * TK + wk4] = wv4;
            float s4 = (w0 + w1) + (w2 + w3);
            if (p == 0) rS0 += s4; else rS1 += s4;
        }
        __syncthreads();

        // FMA: 4x4 register tile, 4-k grouped LDS reads (8 LDS instr / 64 FMA)
#pragma unroll 4
        for (int k = 0; k < TK; k += 4) {
            float wr[4][4];
#pragma unroll
            for (int rr = 0; rr < 4; ++rr)
                *(float4*)wr[rr] = *(const float4*)&wsh[(r0 + rr) * TK + k];
#pragma unroll
            for (int kk = 0; kk < 4; ++kk) {
                float4 hv = *(const float4*)&hs[(k + kk) * F + c0];
#pragma unroll
                for (int rr = 0; rr < 4; ++rr) {
                    acc[rr][0] += wr[rr][kk] * hv.x;
                    acc[rr][1] += wr[rr][kk] * hv.y;
                    acc[rr][2] += wr[rr][kk] * hv.z;
                    acc[rr][3] += wr[rr][kk] * hv.w;
                }
            }
        }
        __syncthreads();
    }

    float* dst = (split == 0) ? out : pacc1;
#pragma unroll
    for (int rr = 0; rr < 4; ++rr) {
        float4 o = {acc[rr][0], acc[rr][1], acc[rr][2], acc[rr][3]};
        *(float4*)&dst[(size_t)(i0 + r0 + rr) * F + c0] = o;
    }

    // reduce row sums across the 16 threads sharing each row (consecutive lanes)
#pragma unroll
    for (int off = 8; off >= 1; off >>= 1) {
        rS0 += __shfl_down(rS0, off, 16);
        rS1 += __shfl_down(rS1, off, 16);
    }
    if ((t & 15) == 0) {
        pS[split * N + i0 + wi] = rS0;
        pS[split * N + i0 + wi + 16] = rS1;
    }
}

// ---------------- K4: out = (out + pacc1) / (pS0 + pS1) ----------------
__global__ __launch_bounds__(256) void finalize(float* __restrict__ out,
                                                const float* __restrict__ pacc1,
                                                const float* __restrict__ pS) {
    const int idx = (blockIdx.x * 256 + threadIdx.x) * 4;
    const int i = idx >> 7;  // / F
    const float s = pS[i] + pS[N + i];
    const float inv = 1.0f / s;
    float4 a0 = *(const float4*)&out[idx];
    float4 a1 = *(const float4*)&pacc1[idx];
    float4 o = {(a0.x + a1.x) * inv, (a0.y + a1.y) * inv,
                (a0.z + a1.z) * inv, (a0.w + a1.w) * inv};
    *(float4*)&out[idx] = o;
}

extern "C" void kernel_launch(void* const* d_in, const int* in_sizes, int n_in,
                              void* d_out, int out_size, void* d_ws, size_t ws_size,
                              hipStream_t stream) {
    (void)in_sizes; (void)n_in; (void)out_size; (void)ws_size;
    const float* x   = (const float*)d_in[0];
    const int*   adj = (const int*)d_in[1];
    const float* W   = (const float*)d_in[2];
    const float* a   = (const float*)d_in[3];
    float* out = (float*)d_out;

    float* ws    = (float*)d_ws;
    float* h     = ws;                  // N*F floats (4 MB)
    float* ssrc  = h + (size_t)N * F;   // N
    float* sdst  = ssrc + N;            // N
    float* pS    = sdst + N;            // 2*N
    float* pacc1 = pS + 2 * N;          // N*F (4 MB)

    gemm_h<<<N / TM, 256, 0, stream>>>(x, W, h);
    scores<<<N / 4, 256, 0, stream>>>(h, a, ssrc, sdst);
    attn_kernel<<<dim3(N / TM, 2), 256, 0, stream>>>(adj, h, ssrc, sdst, out, pacc1, pS);
    finalize<<<(N * F / 4) / 256, 256, 0, stream>>>(out, pacc1, pS);
}

// Round 2
// 413.423 us; speedup vs baseline: 1.4446x; 1.4446x over previous
//
#include <hip/hip_runtime.h>

#define N 8192
#define F 128
#define ALPHA 0.2f

typedef __attribute__((ext_vector_type(8))) short short8;
typedef __attribute__((ext_vector_type(4))) float f32x4;
typedef unsigned short u16;

__device__ __forceinline__ u16 f2bf(float f) {
    unsigned int u = __float_as_uint(f);
    u += 0x7fff + ((u >> 16) & 1);  // RNE; inputs are finite, no NaN handling needed
    return (u16)(u >> 16);
}
__device__ __forceinline__ float bf2f(u16 b) {
    return __uint_as_float(((unsigned int)b) << 16);
}
__device__ __forceinline__ float lrelu(float z) { return fmaxf(z, ALPHA * z); }

// ---------------- K1: h = x@W ; emit hT (bf16, [feature][node]) + ssrc/sdst (fp32) ----------------
__global__ __launch_bounds__(256) void gemm_h(const float* __restrict__ x,
                                              const float* __restrict__ W,
                                              const float* __restrict__ aa,
                                              u16* __restrict__ hT,
                                              float* __restrict__ ssrc,
                                              float* __restrict__ sdst) {
    __shared__ float xs[32 * 128];
    __shared__ float Wsh[32 * 128];
    const int t = threadIdx.x;
    const int i0 = blockIdx.x * 32;
    const int c4 = (t & 31) * 4;
    const int r8 = t >> 5;

#pragma unroll
    for (int p = 0; p < 4; ++p) {
        int rr = p * 8 + r8;
        *(float4*)&xs[rr * 128 + c4] = *(const float4*)&x[(size_t)(i0 + rr) * 128 + c4];
    }

    const int tx = t & 31, ty = t >> 5;
    const int r0 = ty * 4, c0 = tx * 4;
    float acc[4][4] = {};

    for (int kc = 0; kc < 4; ++kc) {
        __syncthreads();
#pragma unroll
        for (int p = 0; p < 4; ++p) {
            int k = p * 8 + r8;
            *(float4*)&Wsh[k * 128 + c4] = *(const float4*)&W[(kc * 32 + k) * 128 + c4];
        }
        __syncthreads();
#pragma unroll 4
        for (int k = 0; k < 32; k += 4) {
            float xr[4][4];
#pragma unroll
            for (int rr = 0; rr < 4; ++rr)
                *(float4*)xr[rr] = *(const float4*)&xs[(r0 + rr) * 128 + kc * 32 + k];
#pragma unroll
            for (int kk = 0; kk < 4; ++kk) {
                float4 wv = *(const float4*)&Wsh[(k + kk) * 128 + c0];
#pragma unroll
                for (int rr = 0; rr < 4; ++rr) {
                    acc[rr][0] += xr[rr][kk] * wv.x;
                    acc[rr][1] += xr[rr][kk] * wv.y;
                    acc[rr][2] += xr[rr][kk] * wv.z;
                    acc[rr][3] += xr[rr][kk] * wv.w;
                }
            }
        }
    }

    // epilogue 1: hT bf16 transposed store (64B contiguous per (block,col) across ty/rr)
#pragma unroll
    for (int rr = 0; rr < 4; ++rr)
#pragma unroll
        for (int cc = 0; cc < 4; ++cc)
            hT[(size_t)(c0 + cc) * N + (i0 + r0 + rr)] = f2bf(acc[rr][cc]);

    // epilogue 2: fused scores s_src/s_dst from full-precision accumulators
    float4 asv = *(const float4*)&aa[c0];
    float4 adv = *(const float4*)&aa[F + c0];
#pragma unroll
    for (int rr = 0; rr < 4; ++rr) {
        float vs = acc[rr][0] * asv.x + acc[rr][1] * asv.y + acc[rr][2] * asv.z + acc[rr][3] * asv.w;
        float vd = acc[rr][0] * adv.x + acc[rr][1] * adv.y + acc[rr][2] * adv.z + acc[rr][3] * adv.w;
#pragma unroll
        for (int off = 16; off >= 1; off >>= 1) {
            vs += __shfl_down(vs, off, 32);
            vd += __shfl_down(vd, off, 32);
        }
        if (tx == 0) {
            ssrc[i0 + r0 + rr] = vs;
            sdst[i0 + r0 + rr] = vd;
        }
    }
}

// ---------------- K2: attention via bf16 MFMA, adj->A-frags computed in-lane ----------------
// Block: 32 i-rows, 4 waves. Wave w produces A-frag-set (rt=w&1, ks=w>>1) directly from adj,
// consumes all 4 frag-sets for feature cols [w*32, w*32+32). grid (N/32, 2 j-splits).
__global__ __launch_bounds__(256, 2) void attn_mfma(const int* __restrict__ adj,
                                                    const u16* __restrict__ hT,
                                                    const float* __restrict__ ssrc,
                                                    const float* __restrict__ sdst,
                                                    float* __restrict__ out,
                                                    float* __restrict__ pacc1,
                                                    float* __restrict__ pS) {
    __shared__ short8 wsh[2][4][64];   // 8 KB: [buf][frag-set rt*2+ks][lane]
    __shared__ float srow[2][2][16];

    const int t = threadIdx.x;
    const int w = t >> 6, L = t & 63;
    const int quad = L >> 4, l16 = L & 15;
    const int i0 = blockIdx.x * 32;
    const int split = blockIdx.y;
    const int jbase = split * (N / 2);
    const int NC = (N / 2) / 64;

    const int rt = w & 1, ks = w >> 1;
    const int fragid = rt * 2 + ks;
    const int prow = i0 + rt * 16 + l16;
    const float s_i = ssrc[prow];

    const int* pA = adj + (size_t)prow * N + jbase + ks * 32 + quad * 8;
    const float* pD = sdst + jbase + ks * 32 + quad * 8;
    const u16* pB = hT + (size_t)(w * 32 + l16) * N + jbase + quad * 8;

    f32x4 acc[2][2];
#pragma unroll
    for (int a = 0; a < 2; ++a)
#pragma unroll
        for (int b = 0; b < 2; ++b) acc[a][b] = 0.f;
    float rsum = 0.f;

    // compute 8 w values -> bf16 frag + rowsum (uses bf16-rounded values so S matches PV exactly)
    auto compute_write = [&](int buf, int4 a0, int4 a1, float4 d0, float4 d1) {
        int m[8] = {a0.x, a0.y, a0.z, a0.w, a1.x, a1.y, a1.z, a1.w};
        float d[8] = {d0.x, d0.y, d0.z, d0.w, d1.x, d1.y, d1.z, d1.w};
        short8 pk;
        float s = 0.f;
#pragma unroll
        for (int k = 0; k < 8; ++k) {
            float e = __expf(lrelu(s_i + d[k]));
            float wv = (m[k] > 0) ? e : 0.f;
            u16 b = f2bf(wv);
            s += bf2f(b);
            pk[k] = (short)b;
        }
        rsum += s;
        wsh[buf][fragid][L] = pk;
    };

    // ---- prologue: chunk 0 ----
    int4 aC0 = *(const int4*)(pA);
    int4 aC1 = *(const int4*)(pA + 4);
    float4 dC0 = *(const float4*)(pD);
    float4 dC1 = *(const float4*)(pD + 4);
    compute_write(0, aC0, aC1, dC0, dC1);

    short8 Bbuf[2][2];
#pragma unroll
    for (int c2 = 0; c2 < 2; ++c2)
#pragma unroll
        for (int kb = 0; kb < 2; ++kb)
            Bbuf[c2][kb] = *(const short8*)(pB + (size_t)c2 * 16 * N + kb * 32);

    // prefetch chunk 1 adj/sdst
    int4 aN0 = *(const int4*)(pA + 64);
    int4 aN1 = *(const int4*)(pA + 64 + 4);
    float4 dN0 = *(const float4*)(pD + 64);
    float4 dN1 = *(const float4*)(pD + 64 + 4);

    for (int c = 1; c < NC; ++c) {
        __syncthreads();  // wsh[(c-1)&1] ready; buf (c&1) readers (chunk c-2) long done
        const int coff = c * 64;

        // B(c) loads in flight across this iteration (consumed next iter / epilogue)
        short8 Bload[2][2];
#pragma unroll
        for (int c2 = 0; c2 < 2; ++c2)
#pragma unroll
            for (int kb = 0; kb < 2; ++kb)
                Bload[c2][kb] = *(const short8*)(pB + (size_t)c2 * 16 * N + kb * 32 + coff);

        // prefetch adj/sdst for chunk c+1 (clamped; redundant final load is harmless)
        const int cn = (c + 1 < NC) ? c + 1 : NC - 1;
        int4 aP0 = *(const int4*)(pA + cn * 64);
        int4 aP1 = *(const int4*)(pA + cn * 64 + 4);
        float4 dP0 = *(const float4*)(pD + cn * 64);
        float4 dP1 = *(const float4*)(pD + cn * 64 + 4);

        // MFMA chunk c-1
        short8 af[4];
#pragma unroll
        for (int fs = 0; fs < 4; ++fs) af[fs] = wsh[(c - 1) & 1][fs][L];
#pragma unroll
        for (int c2 = 0; c2 < 2; ++c2)
#pragma unroll
            for (int rc = 0; rc < 2; ++rc)
#pragma unroll
                for (int kb = 0; kb < 2; ++kb)
                    acc[c2][rc] = __builtin_amdgcn_mfma_f32_16x16x32_bf16(
                        af[rc * 2 + kb], Bbuf[c2][kb], acc[c2][rc], 0, 0, 0);

        // w(c) from regs loaded last iteration
        compute_write(c & 1, aN0, aN1, dN0, dN1);

        // rotate
        aN0 = aP0; aN1 = aP1; dN0 = dP0; dN1 = dP1;
#pragma unroll
        for (int c2 = 0; c2 < 2; ++c2)
#pragma unroll
            for (int kb = 0; kb < 2; ++kb) Bbuf[c2][kb] = Bload[c2][kb];
    }

    // ---- epilogue: MFMA last chunk ----
    __syncthreads();
    {
        short8 af[4];
#pragma unroll
        for (int fs = 0; fs < 4; ++fs) af[fs] = wsh[(NC - 1) & 1][fs][L];
#pragma unroll
        for (int c2 = 0; c2 < 2; ++c2)
#pragma unroll
            for (int rc = 0; rc < 2; ++rc)
#pragma unroll
                for (int kb = 0; kb < 2; ++kb)
                    acc[c2][rc] = __builtin_amdgcn_mfma_f32_16x16x32_bf16(
                        af[rc * 2 + kb], Bbuf[c2][kb], acc[c2][rc], 0, 0, 0);
    }

    // store partials: D layout col=lane&15, row=quad*4+reg
    float* dst = split ? pacc1 : out;
#pragma unroll
    for (int c2 = 0; c2 < 2; ++c2) {
        const int col = (w * 2 + c2) * 16 + l16;
#pragma unroll
        for (int rc = 0; rc < 2; ++rc) {
            const int row0 = i0 + rc * 16 + quad * 4;
#pragma unroll
            for (int r = 0; r < 4; ++r)
                dst[(size_t)(row0 + r) * F + col] = acc[c2][rc][r];
        }
    }

    // row sums: butterfly over quads, then combine the two ks-waves via LDS
    rsum += __shfl_xor(rsum, 16);
    rsum += __shfl_xor(rsum, 32);
    if (L < 16) srow[rt][ks][l16] = rsum;
    __syncthreads();
    if (t < 32) pS[split * N + i0 + t] = srow[t >> 4][0][t & 15] + srow[t >> 4][1][t & 15];
}

// ---------------- K3: out = (out + pacc1) / (pS0 + pS1) ----------------
__global__ __launch_bounds__(256) void finalize(float* __restrict__ out,
                                                const float* __restrict__ pacc1,
                                                const float* __restrict__ pS) {
    const int idx = (blockIdx.x * 256 + threadIdx.x) * 4;
    const int i = idx >> 7;
    const float inv = 1.0f / (pS[i] + pS[N + i]);
    float4 a0 = *(const float4*)&out[idx];
    float4 a1 = *(const float4*)&pacc1[idx];
    float4 o = {(a0.x + a1.x) * inv, (a0.y + a1.y) * inv,
                (a0.z + a1.z) * inv, (a0.w + a1.w) * inv};
    *(float4*)&out[idx] = o;
}

extern "C" void kernel_launch(void* const* d_in, const int* in_sizes, int n_in,
                              void* d_out, int out_size, void* d_ws, size_t ws_size,
                              hipStream_t stream) {
    (void)in_sizes; (void)n_in; (void)out_size; (void)ws_size;
    const float* x   = (const float*)d_in[0];
    const int*   adj = (const int*)d_in[1];
    const float* W   = (const float*)d_in[2];
    const float* a   = (const float*)d_in[3];
    float* out = (float*)d_out;

    u16* hT     = (u16*)d_ws;                    // N*F bf16 (2 MB)
    float* ssrc = (float*)(hT + (size_t)N * F);  // N
    float* sdst = ssrc + N;                      // N
    float* pS   = sdst + N;                      // 2N
    float* pacc1 = pS + 2 * N;                   // N*F fp32 (4 MB)

    gemm_h<<<N / 32, 256, 0, stream>>>(x, W, a, hT, ssrc, sdst);
    attn_mfma<<<dim3(N / 32, 2), 256, 0, stream>>>(adj, hT, ssrc, sdst, out, pacc1, pS);
    finalize<<<(N * F / 4) / 256, 256, 0, stream>>>(out, pacc1, pS);
}